// Round 1
// baseline (1031.841 us; speedup 1.0000x reference)
//
#include <hip/hip_runtime.h>
#include <cstddef>

#define SCALE_F 0.17677669529663687f   // 1/sqrt(32)

// ---------------------------------------------------------------------------
// Kernel 1: fused QKV projection.  out[i][j] = sum_d x[i][d]*W[j][d] + b[j]
// scattered into [B][H][N][DK] layout.  Tile 64x64, 256 thr, 4x4 micro.
// ---------------------------------------------------------------------------
__global__ __launch_bounds__(256) void qkv_gemm(
    const float* __restrict__ x,
    const float* __restrict__ Wq, const float* __restrict__ bq,
    const float* __restrict__ Wk, const float* __restrict__ bk,
    const float* __restrict__ Wv, const float* __restrict__ bv,
    float* __restrict__ Qbuf, float* __restrict__ Kbuf, float* __restrict__ Vbuf)
{
    __shared__ float As[64][68];   // pad 68 keeps float4 alignment, breaks bank stride
    __shared__ float Bs[64][68];
    const int i0  = blockIdx.x * 64;
    const int bj  = blockIdx.y;          // 0..11
    const int wsel = bj >> 2;            // 0=Q 1=K 2=V
    const int jb  = (bj & 3) * 64;
    const float* __restrict__ W    = (wsel == 0) ? Wq : (wsel == 1) ? Wk : Wv;
    const float* __restrict__ bias = (wsel == 0) ? bq : (wsel == 1) ? bk : bv;
    float* __restrict__ out        = (wsel == 0) ? Qbuf : (wsel == 1) ? Kbuf : Vbuf;

    const int t  = threadIdx.x;
    const int tr = t >> 4, tc = t & 15;

    float acc[4][4] = {};

    for (int d0 = 0; d0 < 256; d0 += 64) {
        #pragma unroll
        for (int ph = 0; ph < 4; ++ph) {
            int id = ph * 256 + t;            // float4 id 0..1023
            int r  = id >> 4;
            int c4 = (id & 15) << 2;
            *(float4*)&As[r][c4] = *(const float4*)&x[(size_t)(i0 + r) * 256 + d0 + c4];
            *(float4*)&Bs[r][c4] = *(const float4*)&W[(size_t)(jb + r) * 256 + d0 + c4];
        }
        __syncthreads();
        #pragma unroll 4
        for (int dd = 0; dd < 64; dd += 4) {
            float4 av[4], bv4[4];
            #pragma unroll
            for (int ii = 0; ii < 4; ++ii) av[ii]  = *(float4*)&As[tr + 16*ii][dd];
            #pragma unroll
            for (int jj = 0; jj < 4; ++jj) bv4[jj] = *(float4*)&Bs[tc + 16*jj][dd];
            #pragma unroll
            for (int ii = 0; ii < 4; ++ii)
                #pragma unroll
                for (int jj = 0; jj < 4; ++jj)
                    acc[ii][jj] += av[ii].x*bv4[jj].x + av[ii].y*bv4[jj].y
                                 + av[ii].z*bv4[jj].z + av[ii].w*bv4[jj].w;
        }
        __syncthreads();
    }

    #pragma unroll
    for (int ii = 0; ii < 4; ++ii) {
        int i  = i0 + tr + 16*ii;            // 0..4095
        int b_ = i >> 10, n = i & 1023;
        #pragma unroll
        for (int jj = 0; jj < 4; ++jj) {
            int j  = jb + tc + 16*jj;        // 0..255
            int hh = j >> 5, dk = j & 31;
            out[(((size_t)(b_*8 + hh)) * 1024 + n) * 32 + dk] = acc[ii][jj] + bias[j];
        }
    }
}

// ---------------------------------------------------------------------------
// Kernel 2: fused flash attention.
// grid (16,8,4) = (q-blocks of 64, H, B); block 256 = 4 waves.
// Each lane owns one q row (Q,O in VGPRs); waves split k 4-way (256 each),
// merged via LDS at the end.  K/V rows read as wave-broadcast float4 loads
// (L2-resident); bias rows read per-lane float4 (lines fully consumed).
// Masked scores = -1e38 (self-correcting online softmax; all-masked row -> 0).
// ---------------------------------------------------------------------------
__global__ __launch_bounds__(256) void attn_kernel(
    const float* __restrict__ Qbuf, const float* __restrict__ Kbuf,
    const float* __restrict__ Vbuf,
    const float* __restrict__ ebias, const float* __restrict__ sbias,
    const float* __restrict__ rbias,
    const int* __restrict__ mask, float* __restrict__ attout)
{
    __shared__ float Osh[4][64][33];   // pad 33: (lane+d)%32 -> 2-way (free)
    __shared__ float msh[4][64];
    __shared__ float lsh[4][64];

    const int qb = blockIdx.x, h = blockIdx.y, b = blockIdx.z;
    const int t = threadIdx.x;
    const int w = t >> 6, lane = t & 63;
    const int q  = qb * 64 + lane;
    const int bh = b * 8 + h;

    // Q row, pre-scaled by SCALE
    const float* __restrict__ qp = Qbuf + (size_t)(bh * 1024 + q) * 32;
    float Qs[32];
    #pragma unroll
    for (int i = 0; i < 8; ++i) {
        float4 v = *(const float4*)(qp + 4*i);
        Qs[4*i+0] = v.x * SCALE_F; Qs[4*i+1] = v.y * SCALE_F;
        Qs[4*i+2] = v.z * SCALE_F; Qs[4*i+3] = v.w * SCALE_F;
    }

    float O[32];
    #pragma unroll
    for (int d = 0; d < 32; ++d) O[d] = 0.f;
    float m = -1e38f, l = 0.f;

    const size_t rowbase = (size_t)(bh * 1024 + q) * 1024;
    const float* __restrict__ ebp = ebias + rowbase;
    const float* __restrict__ sbp = sbias + rowbase;
    const float* __restrict__ rbp = rbias + rowbase;
    const int*   __restrict__ mp  = mask + b * 1024;
    const float* __restrict__ Kbase = Kbuf + (size_t)bh * 1024 * 32;
    const float* __restrict__ Vbase = Vbuf + (size_t)bh * 1024 * 32;

    for (int kt = 0; kt < 8; ++kt) {            // 8 tiles of 32 k in this wave's quarter
        const int k0 = w * 256 + kt * 32;
        float s[32];
        // bias sum + mask (masked stays -1e38 even after += dot, |dot| << 1e38)
        #pragma unroll
        for (int i = 0; i < 8; ++i) {
            float4 e4 = *(const float4*)(ebp + k0 + 4*i);
            float4 s4 = *(const float4*)(sbp + k0 + 4*i);
            float4 r4 = *(const float4*)(rbp + k0 + 4*i);
            int4   m4 = *(const int4*)(mp + k0 + 4*i);
            s[4*i+0] = m4.x ? -1e38f : (e4.x + s4.x + r4.x);
            s[4*i+1] = m4.y ? -1e38f : (e4.y + s4.y + r4.y);
            s[4*i+2] = m4.z ? -1e38f : (e4.z + s4.z + r4.z);
            s[4*i+3] = m4.w ? -1e38f : (e4.w + s4.w + r4.w);
        }
        // QK^T: K row broadcast to all lanes
        #pragma unroll
        for (int kk = 0; kk < 32; ++kk) {
            const float4* kr = (const float4*)(Kbase + (size_t)(k0 + kk) * 32);
            float dot = 0.f;
            #pragma unroll
            for (int i = 0; i < 8; ++i) {
                float4 kv = kr[i];
                dot += Qs[4*i+0]*kv.x + Qs[4*i+1]*kv.y
                     + Qs[4*i+2]*kv.z + Qs[4*i+3]*kv.w;
            }
            s[kk] += dot;
        }
        // online softmax (per-tile batching)
        float tm = s[0];
        #pragma unroll
        for (int kk = 1; kk < 32; ++kk) tm = fmaxf(tm, s[kk]);
        float mnew = fmaxf(m, tm);
        float sc = __expf(m - mnew);
        m = mnew;
        l *= sc;
        #pragma unroll
        for (int d = 0; d < 32; ++d) O[d] *= sc;
        // PV
        #pragma unroll
        for (int kk = 0; kk < 32; ++kk) {
            float p = __expf(s[kk] - m);
            l += p;
            const float4* vr = (const float4*)(Vbase + (size_t)(k0 + kk) * 32);
            #pragma unroll
            for (int i = 0; i < 8; ++i) {
                float4 vv = vr[i];
                O[4*i+0] += p * vv.x; O[4*i+1] += p * vv.y;
                O[4*i+2] += p * vv.z; O[4*i+3] += p * vv.w;
            }
        }
    }

    // write partials, merge 4 k-splits
    #pragma unroll
    for (int d = 0; d < 32; ++d) Osh[w][lane][d] = O[d];
    msh[w][lane] = m;
    lsh[w][lane] = l;
    __syncthreads();

    const int qhat = t >> 2;
    const int cb   = (t & 3) * 8;
    float m0 = msh[0][qhat], m1 = msh[1][qhat], m2 = msh[2][qhat], m3 = msh[3][qhat];
    float M  = fmaxf(fmaxf(m0, m1), fmaxf(m2, m3));
    float e0 = __expf(m0 - M), e1 = __expf(m1 - M);
    float e2 = __expf(m2 - M), e3 = __expf(m3 - M);
    float L  = lsh[0][qhat]*e0 + lsh[1][qhat]*e1 + lsh[2][qhat]*e2 + lsh[3][qhat]*e3;
    float inv = (M <= -1e37f) ? 0.f : 1.f / L;   // fully-masked row -> 0 (nan_to_num)
    float* __restrict__ op = attout + (size_t)(b * 1024 + qb * 64 + qhat) * 256 + h * 32;
    #pragma unroll
    for (int j0 = 0; j0 < 8; j0 += 4) {
        float4 r;
        r.x = (Osh[0][qhat][cb+j0+0]*e0 + Osh[1][qhat][cb+j0+0]*e1
             + Osh[2][qhat][cb+j0+0]*e2 + Osh[3][qhat][cb+j0+0]*e3) * inv;
        r.y = (Osh[0][qhat][cb+j0+1]*e0 + Osh[1][qhat][cb+j0+1]*e1
             + Osh[2][qhat][cb+j0+1]*e2 + Osh[3][qhat][cb+j0+1]*e3) * inv;
        r.z = (Osh[0][qhat][cb+j0+2]*e0 + Osh[1][qhat][cb+j0+2]*e1
             + Osh[2][qhat][cb+j0+2]*e2 + Osh[3][qhat][cb+j0+2]*e3) * inv;
        r.w = (Osh[0][qhat][cb+j0+3]*e0 + Osh[1][qhat][cb+j0+3]*e1
             + Osh[2][qhat][cb+j0+3]*e2 + Osh[3][qhat][cb+j0+3]*e3) * inv;
        *(float4*)(op + cb + j0) = r;
    }
}

// ---------------------------------------------------------------------------
// Kernel 3: output projection.  out[i][j] = sum_d A[i][d]*Wo[j][d] + bo[j]
// ---------------------------------------------------------------------------
__global__ __launch_bounds__(256) void oproj_gemm(
    const float* __restrict__ A, const float* __restrict__ W,
    const float* __restrict__ bias, float* __restrict__ out)
{
    __shared__ float As[64][68];
    __shared__ float Bs[64][68];
    const int i0 = blockIdx.x * 64;
    const int jb = blockIdx.y * 64;
    const int t  = threadIdx.x;
    const int tr = t >> 4, tc = t & 15;
    float acc[4][4] = {};

    for (int d0 = 0; d0 < 256; d0 += 64) {
        #pragma unroll
        for (int ph = 0; ph < 4; ++ph) {
            int id = ph * 256 + t;
            int r  = id >> 4;
            int c4 = (id & 15) << 2;
            *(float4*)&As[r][c4] = *(const float4*)&A[(size_t)(i0 + r) * 256 + d0 + c4];
            *(float4*)&Bs[r][c4] = *(const float4*)&W[(size_t)(jb + r) * 256 + d0 + c4];
        }
        __syncthreads();
        #pragma unroll 4
        for (int dd = 0; dd < 64; dd += 4) {
            float4 av[4], bv4[4];
            #pragma unroll
            for (int ii = 0; ii < 4; ++ii) av[ii]  = *(float4*)&As[tr + 16*ii][dd];
            #pragma unroll
            for (int jj = 0; jj < 4; ++jj) bv4[jj] = *(float4*)&Bs[tc + 16*jj][dd];
            #pragma unroll
            for (int ii = 0; ii < 4; ++ii)
                #pragma unroll
                for (int jj = 0; jj < 4; ++jj)
                    acc[ii][jj] += av[ii].x*bv4[jj].x + av[ii].y*bv4[jj].y
                                 + av[ii].z*bv4[jj].z + av[ii].w*bv4[jj].w;
        }
        __syncthreads();
    }

    #pragma unroll
    for (int ii = 0; ii < 4; ++ii) {
        int i = i0 + tr + 16*ii;
        #pragma unroll
        for (int jj = 0; jj < 4; ++jj) {
            int j = jb + tc + 16*jj;
            out[(size_t)i * 256 + j] = acc[ii][jj] + bias[j];
        }
    }
}

// ---------------------------------------------------------------------------
extern "C" void kernel_launch(void* const* d_in, const int* in_sizes, int n_in,
                              void* d_out, int out_size, void* d_ws, size_t ws_size,
                              hipStream_t stream)
{
    const float* x     = (const float*)d_in[0];
    const float* ebias = (const float*)d_in[1];
    const float* sbias = (const float*)d_in[2];
    const float* rbias = (const float*)d_in[3];
    const int*   mask  = (const int*)d_in[4];
    const float* Wq = (const float*)d_in[5];  const float* bq = (const float*)d_in[6];
    const float* Wk = (const float*)d_in[7];  const float* bk = (const float*)d_in[8];
    const float* Wv = (const float*)d_in[9];  const float* bv = (const float*)d_in[10];
    const float* Wo = (const float*)d_in[11]; const float* bo = (const float*)d_in[12];
    float* out = (float*)d_out;

    float* ws = (float*)d_ws;
    float* Qbuf    = ws;                 // 4*8*1024*32 = 1048576 floats
    float* Kbuf    = ws + 1048576;
    float* Vbuf    = ws + 2097152;
    float* attnout = ws + 3145728;       // [B][N][D] = 1048576 floats

    qkv_gemm<<<dim3(64, 12), 256, 0, stream>>>(x, Wq, bq, Wk, bk, Wv, bv,
                                               Qbuf, Kbuf, Vbuf);
    attn_kernel<<<dim3(16, 8, 4), 256, 0, stream>>>(Qbuf, Kbuf, Vbuf,
                                                    ebias, sbias, rbias,
                                                    mask, attnout);
    oproj_gemm<<<dim3(64, 4), 256, 0, stream>>>(attnout, Wo, bo, out);
}